// Round 9
// baseline (42.580 us; speedup 1.0000x reference)
//
#include <hip/hip_runtime.h>
#include <hip/hip_bf16.h>
#include <hip/hip_fp16.h>

typedef _Float16 half8 __attribute__((ext_vector_type(8)));
typedef _Float16 half2v __attribute__((ext_vector_type(2)));
typedef float f32x4 __attribute__((ext_vector_type(4)));

#define B_ 4
#define C_ 64
#define O_ 64
#define H_ 128
#define W_ 128
#define HT 8     // tile rows
#define WT 16    // tile cols
#define HALO 3
#define RS 14    // staged rows (HT + 2*HALO)
#define CS 22    // staged cols (WT + 2*HALO)
// xs layout: [pixel][ch], pixel stride 72 f16 = 144B = 9 half8/uint4 slots

// workspace layout (bytes):
//   [0, 92160)                      : f16 weights (wf 36864 + wfm 9216)
//   [92160, 92160+4718592)          : uint2 cwg[512*1152]  packed bilinear wts
//   [+4718592, +2359296)            : uint  crg[512*1152]  rc00|drow<<16|dcol<<24
#define CWG_OFF 92160
#define CRG_OFF (92160 + 512 * 1152 * 8)

__device__ __forceinline__ unsigned pkh(float lo, float hi) {
  half2v v = {(_Float16)lo, (_Float16)hi};
  return __builtin_bit_cast(unsigned, v);
}

// ---------------------------------------------------------------------------
// Kernel 0: pre-build fragment-ready f16 weights in workspace.
// ---------------------------------------------------------------------------
__global__ void build_frags(const float* __restrict__ dw,
                            const float* __restrict__ mw,
                            _Float16* __restrict__ wsb) {
  int t = blockIdx.x * 256 + threadIdx.x;
  if (t < 36864) {
    int j = t & 7, lane = (t >> 3) & 63, ot = (t >> 9) & 3, s = t >> 11;
    int kk = s >> 1, ch = s & 1;
    int o = ot * 16 + (lane & 15);
    int c = ch * 32 + ((lane >> 4) << 3) + j;
    wsb[t] = (_Float16)dw[(o * 64 + c) * 9 + kk];
  } else if (t < 46080) {
    int t2 = t - 36864;
    int j = t2 & 7, lane = (t2 >> 3) & 63, s = t2 >> 9;
    int km = lane & 15;
    int c = (s & 1) * 32 + ((lane >> 4) << 3) + j;
    int tap = s >> 1;
    float v = (km < 9) ? mw[(km * 64 + c) * 9 + tap] : 0.0f;
    wsb[t] = (_Float16)v;
  }
}

// ---------------------------------------------------------------------------
// Kernel A: offset conv + mask conv + bilinear coefficients -> global ws.
// 512 blocks x 512 threads. LDS: 44352 (xs) + 4608 (offl) = 48960 B.
// ---------------------------------------------------------------------------
__global__ __launch_bounds__(512, 4)
void coef_kernel(const float* __restrict__ x,
                 const float* __restrict__ ele,
                 const float* __restrict__ ow,
                 const float* __restrict__ ob,
                 const float* __restrict__ mb,
                 const _Float16* __restrict__ wsb,
                 uint2* __restrict__ cwg,
                 unsigned* __restrict__ crg) {
  __shared__ uint4 xs4[RS * CS * 9];       // 44352 B, f16 data
  __shared__ _Float16 offl[128 * 18];      //  4608 B

  const int tid = threadIdx.x;
  const int lane = tid & 63;
  const int wv = tid >> 6;
  const int pcl = lane & 15;
  const int lq = lane >> 4;

  const int bid = blockIdx.x;
  const int d = ((bid & 7) << 6) + (bid >> 3);   // XCD-bijective swizzle
  const int b = d >> 7;
  const int t7 = d & 127;
  const int r0 = (t7 >> 3) * HT;
  const int c0 = (t7 & 7) * WT;

  // ---- Early: issue offset-conv ele loads (tid < 128, one px each) -------
  float ev[9];
  {
    int tl = tid & 127;
    int pr = tl >> 4, pc = tl & 15;
    int h = r0 + pr, w = c0 + pc;
#pragma unroll
    for (int ty = 0; ty < 3; ++ty)
#pragma unroll
      for (int tx = 0; tx < 3; ++tx) {
        int gy = h - 1 + ty, gx = w - 1 + tx;
        float v = 0.0f;
        if ((unsigned)gy < 128u && (unsigned)gx < 128u)
          v = ele[b * (H_ * W_) + (gy << 7) + gx];
        ev[ty * 3 + tx] = v;
      }
  }

  // ---- Stage x patch to LDS as f16 ----------------------------------------
  {
    _Float16* xsb = (_Float16*)xs4;
    const int c2 = tid >> 4;
    const int pl = tid & 15;
    const float* xb0 = x + b * (C_ * H_ * W_) + (2 * c2) * (H_ * W_);
    const float* xb1 = xb0 + (H_ * W_);
    for (int p = pl; p < RS * CS; p += 16) {
      int row = (p * 2979) >> 16;          // p / 22
      int col = p - row * CS;
      int gy = r0 - HALO + row, gx = c0 - HALO + col;
      float v0 = 0.0f, v1 = 0.0f;
      if ((unsigned)gy < 128u && (unsigned)gx < 128u) {
        int gi = (gy << 7) + gx;
        v0 = xb0[gi];
        v1 = xb1[gi];
      }
      half2v hv = {(_Float16)v0, (_Float16)v1};
      *(half2v*)&xsb[p * 72 + 2 * c2] = hv;
    }
  }

  // ---- Offset conv (1->18ch 3x3), tid < 128 --------------------------------
  if (tid < 128) {
#pragma unroll
    for (int ci = 0; ci < 18; ++ci) {
      float a = ob[ci];
#pragma unroll
      for (int tap = 0; tap < 9; ++tap) a += ev[tap] * ow[ci * 9 + tap];
      offl[tid * 18 + ci] = (_Float16)a;
    }
  }
  __syncthreads();   // xs + offl ready

  // ---- Mask conv via f16 MFMA + fused sigmoid + coef epilogue -------------
  {
    const half8* wfm8 = ((const half8*)wsb) + 4608;
    f32x4 macc = {0.f, 0.f, 0.f, 0.f};
#pragma unroll
    for (int s = 0; s < 18; ++s) {
      const int tap = s >> 1;
      const int chalf = s & 1;
      const int ty = tap / 3, tx = tap - ty * 3;
      half8 aw = wfm8[s * 64 + lane];
      const int csl = chalf * 4 + lq;
      int rc = (wv + (HALO - 1) + ty) * CS + (pcl + (HALO - 1) + tx);
      half8 xv = *(const half8*)(xs4 + rc * 9 + csl);
      macc = __builtin_amdgcn_mfma_f32_16x16x32_f16(aw, xv, macc, 0, 0, 0);
    }
    const int px = wv * 16 + pcl;
    const int h = r0 + wv, w = c0 + pcl;
    const long cbase = (long)d * 1152;
#pragma unroll
    for (int r = 0; r < 4; ++r) {
      int kk = lq * 4 + r;
      if (kk < 9) {
        float a = macc[r] + mb[kk];
        float m = 1.0f / (1.0f + __expf(-a));
        int ky = kk / 3 - 1;
        int kx = kk - (kk / 3) * 3 - 1;
        half2v o2 = *(const half2v*)&offl[px * 18 + kk * 2];
        float py = (float)(h + ky) + (float)o2[0];
        float pxx = (float)(w + kx) + (float)o2[1];
        float fy = floorf(py), fx = floorf(pxx);
        float wy = py - fy, wx = pxx - fx;
        int iy = (int)fy - r0 + HALO;
        int ix = (int)fx - c0 + HALO;
        int vy0 = (unsigned)iy < (unsigned)RS;
        int vy1 = (unsigned)(iy + 1) < (unsigned)RS;
        int vx0 = (unsigned)ix < (unsigned)CS;
        int vx1 = (unsigned)(ix + 1) < (unsigned)CS;
        int cy0 = min(max(iy, 0), RS - 1), cy1 = min(max(iy + 1, 0), RS - 1);
        int cx0 = min(max(ix, 0), CS - 1), cx1 = min(max(ix + 1, 0), CS - 1);
        float wy0 = 1.0f - wy, wx0 = 1.0f - wx;
        float a00 = wy0 * wx0 * m * (float)(vy0 & vx0);
        float a01 = wy0 * wx * m * (float)(vy0 & vx1);
        float a10 = wy * wx0 * m * (float)(vy1 & vx0);
        float a11 = wy * wx * m * (float)(vy1 & vx1);
        int rc00 = cy0 * CS + cx0;
        int drow = (cy1 - cy0) * CS;
        int dcol = cx1 - cx0;
        uint2 cv;
        cv.x = pkh(a00, a01);
        cv.y = pkh(a10, a11);
        cwg[cbase + kk * 128 + px] = cv;
        crg[cbase + kk * 128 + px] =
            (unsigned)rc00 | ((unsigned)drow << 16) | ((unsigned)dcol << 24);
      }
    }
  }
}

// ---------------------------------------------------------------------------
// Kernel B: stage x (L2-warm) -> one barrier -> gather+blend+MFMA -> out.
// 512 blocks x 512 threads. LDS: 44352 B only -> 3 blocks/CU elastic.
// ---------------------------------------------------------------------------
__global__ __launch_bounds__(512, 4)
void gemm_kernel(const float* __restrict__ x,
                 const _Float16* __restrict__ wsb,
                 const uint2* __restrict__ cwg,
                 const unsigned* __restrict__ crg,
                 float* __restrict__ out) {
  __shared__ uint4 xs4[RS * CS * 9];       // 44352 B

  const int tid = threadIdx.x;
  const int lane = tid & 63;
  const int wv = tid >> 6;
  const int pcl = lane & 15;
  const int lq = lane >> 4;

  const int bid = blockIdx.x;
  const int d = ((bid & 7) << 6) + (bid >> 3);   // same swizzle as kernel A
  const int b = d >> 7;
  const int t7 = d & 127;
  const int r0 = (t7 >> 3) * HT;
  const int c0 = (t7 & 7) * WT;

  const int px = wv * 16 + pcl;

  // ---- Prefetch all 9 coef pairs into registers (L2-local from kernel A) --
  const long cbase = (long)d * 1152 + px;
  uint2 cv0 = cwg[cbase + 0 * 128];
  uint2 cv1 = cwg[cbase + 1 * 128];
  uint2 cv2 = cwg[cbase + 2 * 128];
  uint2 cv3 = cwg[cbase + 3 * 128];
  uint2 cv4 = cwg[cbase + 4 * 128];
  uint2 cv5 = cwg[cbase + 5 * 128];
  uint2 cv6 = cwg[cbase + 6 * 128];
  uint2 cv7 = cwg[cbase + 7 * 128];
  uint2 cv8 = cwg[cbase + 8 * 128];
  unsigned rv0 = crg[cbase + 0 * 128];
  unsigned rv1 = crg[cbase + 1 * 128];
  unsigned rv2 = crg[cbase + 2 * 128];
  unsigned rv3 = crg[cbase + 3 * 128];
  unsigned rv4 = crg[cbase + 4 * 128];
  unsigned rv5 = crg[cbase + 5 * 128];
  unsigned rv6 = crg[cbase + 6 * 128];
  unsigned rv7 = crg[cbase + 7 * 128];
  unsigned rv8 = crg[cbase + 8 * 128];

  // ---- Stage x patch to LDS as f16 (mostly L2 hits after kernel A) --------
  {
    _Float16* xsb = (_Float16*)xs4;
    const int c2 = tid >> 4;
    const int pl = tid & 15;
    const float* xb0 = x + b * (C_ * H_ * W_) + (2 * c2) * (H_ * W_);
    const float* xb1 = xb0 + (H_ * W_);
    for (int p = pl; p < RS * CS; p += 16) {
      int row = (p * 2979) >> 16;          // p / 22
      int col = p - row * CS;
      int gy = r0 - HALO + row, gx = c0 - HALO + col;
      float v0 = 0.0f, v1 = 0.0f;
      if ((unsigned)gy < 128u && (unsigned)gx < 128u) {
        int gi = (gy << 7) + gx;
        v0 = xb0[gi];
        v1 = xb1[gi];
      }
      half2v hv = {(_Float16)v0, (_Float16)v1};
      *(half2v*)&xsb[p * 72 + 2 * c2] = hv;
    }
  }
  __syncthreads();   // the only barrier

  // ---- Gather + blend + MFMA ----------------------------------------------
  const half8* wf8 = (const half8*)wsb;
  f32x4 acc[4];
#pragma unroll
  for (int ot = 0; ot < 4; ++ot) {
    f32x4 z = {0.f, 0.f, 0.f, 0.f};
    acc[ot] = z;
  }

#define KKSTEP(KK, CV, RV)                                                   \
  {                                                                          \
    int rc00 = (RV)&0xFFFF;                                                  \
    int drow = ((RV) >> 16) & 0xFF;                                          \
    int dcol = (RV) >> 24;                                                   \
    int rc01 = rc00 + dcol;                                                  \
    int rc10 = rc00 + drow;                                                  \
    int rc11 = rc10 + dcol;                                                  \
    half2v c01 = __builtin_bit_cast(half2v, (CV).x);                         \
    half2v c23 = __builtin_bit_cast(half2v, (CV).y);                         \
    _Float16 a00 = c01[0], a01 = c01[1], a10 = c23[0], a11 = c23[1];         \
    half8 a00s = {a00, a00, a00, a00, a00, a00, a00, a00};                   \
    half8 a01s = {a01, a01, a01, a01, a01, a01, a01, a01};                   \
    half8 a10s = {a10, a10, a10, a10, a10, a10, a10, a10};                   \
    half8 a11s = {a11, a11, a11, a11, a11, a11, a11, a11};                   \
    _Pragma("unroll")                                                        \
    for (int ch = 0; ch < 2; ++ch) {                                         \
      const int csl = ch * 4 + lq;                                           \
      half8 v00 = *(const half8*)(xs4 + rc00 * 9 + csl);                     \
      half8 v01 = *(const half8*)(xs4 + rc01 * 9 + csl);                     \
      half8 v10 = *(const half8*)(xs4 + rc10 * 9 + csl);                     \
      half8 v11 = *(const half8*)(xs4 + rc11 * 9 + csl);                     \
      half8 t = v00 * a00s + v01 * a01s + v10 * a10s + v11 * a11s;           \
      const int sidx = (KK)*2 + ch;                                          \
      _Pragma("unroll")                                                      \
      for (int ot = 0; ot < 4; ++ot) {                                       \
        half8 bw = wf8[(sidx * 4 + ot) * 64 + lane];                         \
        acc[ot] =                                                            \
            __builtin_amdgcn_mfma_f32_16x16x32_f16(bw, t, acc[ot], 0, 0, 0); \
      }                                                                      \
    }                                                                        \
  }

  KKSTEP(0, cv0, rv0)
  KKSTEP(1, cv1, rv1)
  KKSTEP(2, cv2, rv2)
  KKSTEP(3, cv3, rv3)
  KKSTEP(4, cv4, rv4)
  KKSTEP(5, cv5, rv5)
  KKSTEP(6, cv6, rv6)
  KKSTEP(7, cv7, rv7)
  KKSTEP(8, cv8, rv8)
#undef KKSTEP

  // ---- Epilogue: ReLU -> fp32 -> global ----
  const int h = r0 + wv;
  const int w = c0 + pcl;
#pragma unroll
  for (int ot = 0; ot < 4; ++ot) {
#pragma unroll
    for (int r = 0; r < 4; ++r) {
      int o = ot * 16 + lq * 4 + r;
      float v = fmaxf(acc[ot][r], 0.0f);
      out[((b * O_ + o) << 14) + (h << 7) + w] = v;
    }
  }
}

extern "C" void kernel_launch(void* const* d_in, const int* in_sizes, int n_in,
                              void* d_out, int out_size, void* d_ws, size_t ws_size,
                              hipStream_t stream) {
  const float* x   = (const float*)d_in[0];
  const float* ele = (const float*)d_in[1];
  const float* ow  = (const float*)d_in[2];
  const float* ob  = (const float*)d_in[3];
  const float* mw  = (const float*)d_in[4];
  const float* mb  = (const float*)d_in[5];
  const float* dw  = (const float*)d_in[6];
  _Float16* wsb = (_Float16*)d_ws;
  uint2* cwg = (uint2*)((char*)d_ws + CWG_OFF);
  unsigned* crg = (unsigned*)((char*)d_ws + CRG_OFF);

  build_frags<<<180, 256, 0, stream>>>(dw, mw, wsb);
  coef_kernel<<<512, 512, 0, stream>>>(x, ele, ow, ob, mb, wsb, cwg, crg);
  gemm_kernel<<<512, 512, 0, stream>>>(x, wsb, cwg, crg, (float*)d_out);
}